// Round 1
// baseline (38261.218 us; speedup 1.0000x reference)
//
#include <hip/hip_runtime.h>
#include <hip/hip_cooperative_groups.h>

namespace cg = cooperative_groups;

typedef __attribute__((ext_vector_type(8))) short short8;
typedef __attribute__((ext_vector_type(4))) float floatx4;

#define SEQ 512
#define BS  64
#define HID 1024
#define G4  4096

__device__ __forceinline__ unsigned short f2b(float f) {
  union { float f; unsigned u; } v; v.f = f;
  return (unsigned short)((v.u + 0x7FFFu + ((v.u >> 16) & 1u)) >> 16);
}
__device__ __forceinline__ float b2f(unsigned short s) {
  union { unsigned u; float f; } v; v.u = ((unsigned)s) << 16;
  return v.f;
}

// ---- weight transpose+convert: W[1024][4096] f32 -> WT[4096][1024] bf16
__global__ void wtrans(const float* __restrict__ W, short* __restrict__ WT) {
  __shared__ float tile[32][33];
  const int tx = threadIdx.x, ty = threadIdx.y;
  const int n0 = blockIdx.x << 5, k0 = blockIdx.y << 5;
#pragma unroll
  for (int i = 0; i < 32; i += 8)
    tile[ty + i][tx] = W[(size_t)(k0 + ty + i) * G4 + n0 + tx];
  __syncthreads();
#pragma unroll
  for (int i = 0; i < 32; i += 8)
    WT[(size_t)(n0 + ty + i) * 1024 + k0 + tx] = (short)f2b(tile[tx][ty + i]);
}

// ---- projection GEMM: out[M=32768][4096] = A[M][1024](f32) @ WT^T + bias
// A row-major f32, BT = WT[4096][1024] bf16 (n-major), 128x128 tile, 4 waves.
__global__ __launch_bounds__(256)
void gemm_xw(const float* __restrict__ A, const short* __restrict__ BT,
             const float* __restrict__ bias, void* __restrict__ xw, int xw_f32) {
  __shared__ short Al[128 * 40];
  __shared__ short Bl[128 * 40];
  const int tid = threadIdx.x;
  const int wave = tid >> 6, lane = tid & 63;
  const int lr = lane & 15, lh = lane >> 4;
  const int wm = wave >> 1, wn = wave & 1;
  const int m0 = blockIdx.y << 7;
  const int n0 = blockIdx.x << 7;
  const int arow = tid >> 1, akc = tid & 1;

  const float* aptr = A + (size_t)(m0 + arow) * 1024 + akc * 16;
  const short* bptr = BT + (size_t)(n0 + arow) * 1024 + akc * 16;

  floatx4 acc[4][4] = {};
  floatx4 fa[4];
  short8 pb0, pb1;
#pragma unroll
  for (int j = 0; j < 4; ++j) fa[j] = *(const floatx4*)(aptr + 4 * j);
  pb0 = *(const short8*)(bptr);
  pb1 = *(const short8*)(bptr + 8);

  for (int it = 0; it < 32; ++it) {
    __syncthreads();
    unsigned short us[16];
#pragma unroll
    for (int j = 0; j < 4; ++j)
#pragma unroll
      for (int e = 0; e < 4; ++e) us[4 * j + e] = f2b(fa[j][e]);
    short8 s0, s1;
#pragma unroll
    for (int e = 0; e < 8; ++e) { s0[e] = (short)us[e]; s1[e] = (short)us[8 + e]; }
    *(short8*)&Al[arow * 40 + akc * 16 + 0] = s0;
    *(short8*)&Al[arow * 40 + akc * 16 + 8] = s1;
    *(short8*)&Bl[arow * 40 + akc * 16 + 0] = pb0;
    *(short8*)&Bl[arow * 40 + akc * 16 + 8] = pb1;
    __syncthreads();
    if (it < 31) {
      const int k0 = (it + 1) << 5;
#pragma unroll
      for (int j = 0; j < 4; ++j) fa[j] = *(const floatx4*)(aptr + k0 + 4 * j);
      pb0 = *(const short8*)(bptr + k0);
      pb1 = *(const short8*)(bptr + k0 + 8);
    }
    short8 af[4], bf[4];
#pragma unroll
    for (int mt = 0; mt < 4; ++mt) af[mt] = *(const short8*)&Al[(wm * 64 + mt * 16 + lr) * 40 + lh * 8];
#pragma unroll
    for (int nt = 0; nt < 4; ++nt) bf[nt] = *(const short8*)&Bl[(wn * 64 + nt * 16 + lr) * 40 + lh * 8];
#pragma unroll
    for (int mt = 0; mt < 4; ++mt)
#pragma unroll
      for (int nt = 0; nt < 4; ++nt)
        acc[mt][nt] = __builtin_amdgcn_mfma_f32_16x16x32_bf16(af[mt], bf[nt], acc[mt][nt], 0, 0, 0);
  }
#pragma unroll
  for (int nt = 0; nt < 4; ++nt) {
    const int gcol = n0 + wn * 64 + nt * 16 + lr;
    const float bv = bias[gcol];
#pragma unroll
    for (int mt = 0; mt < 4; ++mt)
#pragma unroll
      for (int r = 0; r < 4; ++r) {
        const int grow = m0 + wm * 64 + mt * 16 + lh * 4 + r;
        const float v = acc[mt][nt][r] + bv;
        if (xw_f32) ((float*)xw)[(size_t)grow * G4 + gcol] = v;
        else        ((unsigned short*)xw)[(size_t)grow * G4 + gcol] = f2b(v);
      }
  }
}

struct ScanArgs {
  const void* xw;          // precomputed input projection (mode 0: bf16, 1: f32)
  const short* wt_hi;      // WT of W_hi [4096][1024] bf16
  const short* wt_in;      // WT of W_in (mode 2 only)
  const void* xsrc;        // x source for fused mode (f32 or bf16)
  const float* bias;
  float* cbuf;             // [64*1024] f32 cell state
  unsigned short* hbuf;    // [2][64*1024] bf16 ping-pong h state
  float* hs_f32;           // hs output f32 (or null)
  unsigned short* hs_b16;  // hs output bf16 (or null)
  float* h_final;          // final h f32 (or null)
  float* c_final;          // final c f32 (or null)
  int mode;                // 0: xw bf16, 1: xw f32, 2: fused (K=2048)
  int xsrc_f32;            // fused mode: x source dtype
};

// ---- persistent cooperative scan: 64 blocks x 256 threads, 1 grid.sync/step.
// Block b owns hidden units [16b,16b+16); wave w computes gate group w.
__global__ __launch_bounds__(256)
void lstm_scan(ScanArgs p) {
  __shared__ short Alds[64 * 40];
  __shared__ short Blds[64 * 40];
  __shared__ float gsm[4 * 64 * 17];
  const int tid = threadIdx.x;
  const int wave = tid >> 6, lane = tid & 63;
  const int lr = lane & 15, lh = lane >> 4;
  const int blk = blockIdx.x;
  const int srow = tid >> 2, skc = tid & 3;
  const int b_grow = ((srow >> 4) << 10) + (blk << 4) + (srow & 15);
  const short* bgp_h = p.wt_hi + (size_t)b_grow * 1024 + skc * 8;
  const short* bgp_x = p.wt_in + (size_t)b_grow * 1024 + skc * 8;
  const int nit = (p.mode == 2) ? 64 : 32;
  cg::grid_group grid = cg::this_grid();

  for (int t = 0; t < SEQ; ++t) {
    const unsigned short* hb = p.hbuf + (t & 1) * (BS * HID);
    unsigned short* hw = p.hbuf + ((t + 1) & 1) * (BS * HID);

    auto load_a = [&](int it2) -> short8 {
      if (it2 < 32) {
        return *(const short8*)(hb + srow * 1024 + (it2 << 5) + skc * 8);
      } else {
        const int ko = ((it2 - 32) << 5) + skc * 8;
        if (p.xsrc_f32) {
          const float* xs = (const float*)p.xsrc + ((size_t)t * BS + srow) * 1024 + ko;
          floatx4 f0 = *(const floatx4*)xs;
          floatx4 f1 = *(const floatx4*)(xs + 4);
          short8 s;
#pragma unroll
          for (int e = 0; e < 4; ++e) { s[e] = (short)f2b(f0[e]); s[4 + e] = (short)f2b(f1[e]); }
          return s;
        } else {
          const unsigned short* xs = (const unsigned short*)p.xsrc + ((size_t)t * BS + srow) * 1024 + ko;
          return *(const short8*)xs;
        }
      }
    };
    auto load_b = [&](int it2) -> short8 {
      return (it2 < 32) ? *(const short8*)(bgp_h + (it2 << 5))
                        : *(const short8*)(bgp_x + ((it2 - 32) << 5));
    };

    floatx4 acc[4] = {};
    short8 pa = load_a(0);
    short8 pb = load_b(0);
    for (int it = 0; it < nit; ++it) {
      __syncthreads();
      *(short8*)&Alds[srow * 40 + skc * 8] = pa;
      *(short8*)&Blds[srow * 40 + skc * 8] = pb;
      __syncthreads();
      if (it + 1 < nit) { pa = load_a(it + 1); pb = load_b(it + 1); }
      const short8 bfr = *(const short8*)&Blds[(wave * 16 + lr) * 40 + lh * 8];
#pragma unroll
      for (int m = 0; m < 4; ++m) {
        const short8 afr = *(const short8*)&Alds[(m * 16 + lr) * 40 + lh * 8];
        acc[m] = __builtin_amdgcn_mfma_f32_16x16x32_bf16(afr, bfr, acc[m], 0, 0, 0);
      }
    }
    // gates: add xw (or bias in fused mode), exchange via LDS
    const int col = (wave << 10) + (blk << 4) + lr;
#pragma unroll
    for (int m = 0; m < 4; ++m)
#pragma unroll
      for (int r = 0; r < 4; ++r) {
        const int b = m * 16 + lh * 4 + r;
        float xv;
        if (p.mode == 2) xv = p.bias[col];
        else {
          const size_t idx = ((size_t)t * BS + b) * G4 + col;
          xv = p.mode ? ((const float*)p.xw)[idx] : b2f(((const unsigned short*)p.xw)[idx]);
        }
        gsm[(wave * 64 + b) * 17 + lr] = acc[m][r] + xv;
      }
    __syncthreads();
    // elementwise update: this block's 64 batch x 16 unit slice
#pragma unroll
    for (int i = 0; i < 4; ++i) {
      const int pp = tid + (i << 8);
      const int b = pp >> 4, u = pp & 15;
      const float ig = gsm[(0 * 64 + b) * 17 + u];
      const float fg = gsm[(1 * 64 + b) * 17 + u];
      const float gg = gsm[(2 * 64 + b) * 17 + u];
      const float og = gsm[(3 * 64 + b) * 17 + u];
      const float iv = 1.f / (1.f + __expf(-ig));
      const float fv = 1.f / (1.f + __expf(-fg));
      const float gv = tanhf(gg);
      const float ov = 1.f / (1.f + __expf(-og));
      const int ci = (b << 10) + (blk << 4) + u;
      const float cn = fv * p.cbuf[ci] + iv * gv;
      p.cbuf[ci] = cn;
      const float hv = ov * tanhf(cn);
      hw[ci] = f2b(hv);
      if (p.hs_f32) p.hs_f32[((size_t)t * BS + b) * HID + (blk << 4) + u] = hv;
      if (p.hs_b16) p.hs_b16[((size_t)t * BS + b) * HID + (blk << 4) + u] = f2b(hv);
      if (p.h_final && t == SEQ - 1) { p.h_final[ci] = hv; p.c_final[ci] = cn; }
    }
    __threadfence();
    grid.sync();
  }
}

extern "C" void kernel_launch(void* const* d_in, const int* in_sizes, int n_in,
                              void* d_out, int out_size, void* d_ws, size_t ws_size,
                              hipStream_t stream) {
  const float* x    = (const float*)d_in[0];
  const float* Wii0 = (const float*)d_in[1];
  const float* Wii  = (const float*)d_in[2];
  const float* Whi  = (const float*)d_in[3];
  const float* bias = (const float*)d_in[4];
  float* out  = (float*)d_out;
  float* hs   = out;                              // [512*64*1024]
  float* hfin = out + (size_t)SEQ * BS * HID;     // [64*1024]
  float* cfin = hfin + BS * HID;                  // [64*1024]

  char* ws = (char*)d_ws;
  short* WT0 = (short*)ws;
  short* WT1 = WT0 + (size_t)G4 * 1024;
  short* WTh = WT1 + (size_t)G4 * 1024;
  unsigned short* hbuf = (unsigned short*)(WTh + (size_t)G4 * 1024);
  float* cbuf = (float*)(hbuf + 2 * BS * HID);
  char* tail = (char*)(cbuf + BS * HID);
  const size_t head = (size_t)(tail - ws);
  const size_t XWF = (size_t)SEQ * BS * G4 * 4;
  const size_t XWB = (size_t)SEQ * BS * G4 * 2;

  int mode;
  if (ws_size >= head + XWF)      mode = 1;  // xw f32
  else if (ws_size >= head + XWB) mode = 0;  // xw bf16
  else                            mode = 2;  // fused projection (needs 64MB for hs1 bf16)

  wtrans<<<dim3(128, 32), dim3(32, 8), 0, stream>>>(Wii0, WT0);
  wtrans<<<dim3(128, 32), dim3(32, 8), 0, stream>>>(Wii, WT1);
  wtrans<<<dim3(128, 32), dim3(32, 8), 0, stream>>>(Whi, WTh);

  for (int layer = 0; layer < 2; ++layer) {
    if (mode != 2) {
      const float* Ain = layer ? hs : x;
      const short* WTl = layer ? WT1 : WT0;
      gemm_xw<<<dim3(32, 256), dim3(256), 0, stream>>>(Ain, WTl, bias, (void*)tail, mode);
    }
    hipMemsetAsync(hbuf, 0, 2 * BS * HID * sizeof(unsigned short), stream);
    hipMemsetAsync(cbuf, 0, BS * HID * sizeof(float), stream);

    ScanArgs sa;
    sa.xw = (const void*)tail;
    sa.wt_hi = WTh;
    sa.wt_in = layer ? WT1 : WT0;
    sa.xsrc = layer ? (const void*)tail : (const void*)x;  // mode 2: hs1 bf16 lives at tail
    sa.bias = bias;
    sa.cbuf = cbuf;
    sa.hbuf = hbuf;
    sa.mode = mode;
    sa.xsrc_f32 = (layer == 0) ? 1 : 0;
    if (mode == 2) {
      if (layer == 0) { sa.hs_f32 = nullptr; sa.hs_b16 = (unsigned short*)tail; }
      else            { sa.hs_f32 = hs;      sa.hs_b16 = nullptr; }
    } else {
      sa.hs_f32 = hs; sa.hs_b16 = nullptr;
    }
    sa.h_final = layer ? hfin : nullptr;
    sa.c_final = layer ? cfin : nullptr;

    void* args[] = { &sa };
    hipLaunchCooperativeKernel(reinterpret_cast<const void*>(lstm_scan),
                               dim3(64), dim3(256), args, 0u, stream);
  }
}